// Round 7
// baseline (3660673.047 us; speedup 1.0000x reference)
//
#include <hip/hip_runtime.h>

// NeuralODESIR round 7: weights in LDS, read wave-uniform.
// r6 post-mortem: 2 waves/SIMD achieved but VALUBusy 34% — the f64 weight
// stream (131KB/eval) misses the ~16KB scalar K$ every eval, SGPR prefetch
// depth ~2 rows -> ~300cy exposed L2 latency per row. Fix: stage ALL params
// (137KB f64) into LDS once per block; weight reads become same-address
// ds_read broadcasts (conflict-free, deeply pipelined on lgkmcnt).
// Geometry: 512-thr blocks, 1 block/CU (LDS 137KB), grid=256 -> 8 waves/CU
// = 2/SIMD. h1 fp32[64] regs + acc3 f64[64] + h2 f64[8] ~= 242 VGPR < 256.
// Numerics = r2/r5/r6 proven: exact f64 MACs (weights are exact f64 widenings
// of the fp32 inputs), fp32 tanhf activations, f64 RK4 state.

#define NW1  (5 * 64)
#define NB1  64
#define NW2  (64 * 128)
#define NB2  128
#define NW3  (128 * 64)
#define NB3  64
#define NW4  (64 * 3)
#define NB4  3

// offsets (in doubles) inside d_ws / LDS
#define oW1T 0                  // [64][5]  (transposed W1)
#define oB1  (oW1T + NW1)       // 320
#define oW2  (oB1 + NB1)        // 384   [64][128] original layout
#define oB2  (oW2 + NW2)        // 8576
#define oW3  (oB2 + NB2)        // 8704  [128][64] original layout
#define oB3  (oW3 + NW3)        // 16896
#define oW4  (oB3 + NB3)        // 16960 [64][3] original layout
#define oB4  (oW4 + NW4)        // 17152
#define NTOT (oB4 + NB4)        // 17155
#define LDS_BYTES (NTOT * 8)    // 137240

__device__ __forceinline__ void store_softmax(float* __restrict__ out, size_t base,
                                              float a, float b, float c) {
    float m  = fmaxf(a, fmaxf(b, c));
    float e0 = expf(a - m);
    float e1 = expf(b - m);
    float e2 = expf(c - m);
    float s  = e0 + e1 + e2;
    out[base + 0] = e0 / s;
    out[base + 1] = e1 / s;
    out[base + 2] = e2 / s;
}

__global__ __launch_bounds__(512, 2) void sir_rk4_kernel(
    const float* __restrict__ y0,   const float* __restrict__ tspan,
    const float* __restrict__ beta, const float* __restrict__ gamma,
    const double* __restrict__ P,
    float* __restrict__ out, int B, int T)
{
    extern __shared__ double WL[];   // all params, f64, 137240 B

    // cooperative one-time stage: global (ws) -> LDS
    for (int idx = threadIdx.x; idx < NTOT; idx += 512)
        WL[idx] = P[idx];
    __syncthreads();

    const int b = blockIdx.x * 512 + threadIdx.x;
    if (b >= B) return;

    double ys = (double)y0[b * 3 + 0];
    double yi = (double)y0[b * 3 + 1];
    double yr = (double)y0[b * 3 + 2];
    const double be = (double)beta[b];
    const double ga = (double)gamma[b];

    store_softmax(out, (size_t)b * 3, (float)ys, (float)yi, (float)yr);

    #pragma unroll 1
    for (int t = 0; t < T - 1; ++t) {
        double dt = (double)tspan[t + 1] - (double)tspan[t];

        double ks0 = 0.0, ks1 = 0.0, ks2 = 0.0;
        double zs = ys, zi = yi, zr = yr;

        #pragma unroll 1
        for (int st = 0; st < 4; ++st) {
            // ---- L1: 5 -> 64 (fully unrolled: h1 must stay in VGPRs) ----
            float h1[64];
            #pragma unroll
            for (int j = 0; j < 64; ++j) {
                const double* w = &WL[oW1T + j * 5];
                double ta = fma(w[0], zs, WL[oB1 + j]);
                double tb = w[2] * zr;
                ta = fma(w[1], zi, ta);
                tb = fma(w[3], be, tb);
                ta = fma(w[4], ga, ta);
                h1[j] = tanhf((float)(ta + tb));
            }

            double acc3[64];
            #pragma unroll
            for (int j = 0; j < 64; ++j) acc3[j] = WL[oB3 + j];

            // ---- L2+L3: 64 -> 128 -> 64 in 16 tiles of 8 ----
            #pragma unroll 1
            for (int c = 0; c < 16; ++c) {
                double h2[8];
                #pragma unroll
                for (int k = 0; k < 8; ++k) h2[k] = WL[oB2 + c * 8 + k];

                #pragma unroll
                for (int i = 0; i < 64; ++i) {
                    double hv = (double)h1[i];
                    const double* w = &WL[oW2 + i * 128 + c * 8];
                    #pragma unroll
                    for (int k = 0; k < 8; ++k)
                        h2[k] = fma(w[k], hv, h2[k]);
                }

                #pragma unroll
                for (int k = 0; k < 8; ++k) {
                    double h = (double)tanhf((float)h2[k]);
                    const double* w3 = &WL[oW3 + (size_t)(c * 8 + k) * 64];
                    #pragma unroll
                    for (int j = 0; j < 64; ++j)
                        acc3[j] = fma(w3[j], h, acc3[j]);
                }
            }

            // ---- L4: 64 -> 3 (fully unrolled: acc3 in VGPRs) ----
            double e0 = WL[oB4 + 0], e1 = WL[oB4 + 1], e2 = WL[oB4 + 2];
            #pragma unroll
            for (int j = 0; j < 64; ++j) {
                double h = (double)tanhf((float)acc3[j]);
                const double* w4 = &WL[oW4 + j * 3];
                e0 = fma(w4[0], h, e0);
                e1 = fma(w4[1], h, e1);
                e2 = fma(w4[2], h, e2);
            }

            double w = (st == 1 || st == 2) ? 2.0 : 1.0;
            ks0 = fma(w, e0, ks0);
            ks1 = fma(w, e1, ks1);
            ks2 = fma(w, e2, ks2);
            double a = (st < 2) ? 0.5 * dt : dt;
            zs = fma(a, e0, ys);
            zi = fma(a, e1, yi);
            zr = fma(a, e2, yr);
        }

        double c6 = dt * (1.0 / 6.0);
        ys = fma(c6, ks0, ys);
        yi = fma(c6, ks1, yi);
        yr = fma(c6, ks2, yr);

        store_softmax(out, ((size_t)(t + 1) * B + b) * 3, (float)ys, (float)yi, (float)yr);
    }
}

// widen all params to fp64 in ws; W1 transposed to [64][5], rest original.
__global__ void stage_params_kernel(
    const float* __restrict__ W1, const float* __restrict__ b1,
    const float* __restrict__ W2, const float* __restrict__ b2,
    const float* __restrict__ W3, const float* __restrict__ b3,
    const float* __restrict__ W4, const float* __restrict__ b4,
    double* __restrict__ P)
{
    int idx = blockIdx.x * blockDim.x + threadIdx.x;
    if (idx >= NTOT) return;
    float v;
    if (idx < oB1)       { int u = idx - oW1T; int j = u / 5; int q = u % 5; v = W1[q * 64 + j]; }
    else if (idx < oW2)  v = b1[idx - oB1];
    else if (idx < oB2)  v = W2[idx - oW2];
    else if (idx < oW3)  v = b2[idx - oB2];
    else if (idx < oB3)  v = W3[idx - oW3];
    else if (idx < oW4)  v = b3[idx - oB3];
    else if (idx < oB4)  v = W4[idx - oW4];
    else                 v = b4[idx - oB4];
    P[idx] = (double)v;
}

extern "C" void kernel_launch(void* const* d_in, const int* in_sizes, int n_in,
                              void* d_out, int out_size, void* d_ws, size_t ws_size,
                              hipStream_t stream) {
    const float* y0    = (const float*)d_in[0];
    const float* tspan = (const float*)d_in[1];
    const float* beta  = (const float*)d_in[2];
    const float* gamma = (const float*)d_in[3];
    const float* W1    = (const float*)d_in[4];
    const float* b1    = (const float*)d_in[5];
    const float* W2    = (const float*)d_in[6];
    const float* b2    = (const float*)d_in[7];
    const float* W3    = (const float*)d_in[8];
    const float* b3    = (const float*)d_in[9];
    const float* W4    = (const float*)d_in[10];
    const float* b4    = (const float*)d_in[11];

    int B = in_sizes[0] / 3;
    int T = in_sizes[1];
    float* out = (float*)d_out;

    double* P = (double*)d_ws;
    stage_params_kernel<<<(NTOT + 255) / 256, 256, 0, stream>>>(
        W1, b1, W2, b2, W3, b3, W4, b4, P);

    // allow >64KB dynamic LDS (host-side attribute set; not a stream op,
    // safe under graph capture; idempotent)
    hipFuncSetAttribute((const void*)sir_rk4_kernel,
                        hipFuncAttributeMaxDynamicSharedMemorySize, LDS_BYTES);

    int blocks = (B + 511) / 512;
    sir_rk4_kernel<<<blocks, 512, LDS_BYTES, stream>>>(
        y0, tspan, beta, gamma, P, out, B, T);
}

// Round 8
// 109498.767 us; speedup vs baseline: 33.4312x; 33.4312x over previous
//
#include <hip/hip_runtime.h>

// NeuralODESIR round 8: r6 structure + f32 weight stream + explicit SGPR prefetch.
// r7 post-mortem: h1->VGPR pushed V+A to ~288 > 256 cap -> acc3 spilled to
// scratch -> 8192 scratch RMW/eval -> 3.66 s. r6 layout (h1-in-LDS f32,
// acc3-in-AGPR, ~224 regs) is the proven fit; do not perturb it.
// r6's own limiter: W2/W3 f64 SMEM stream (132 KB/eval, ~2100 s_loads, 2-3
// outstanding) -> 66% stall. Fixes here, all plain C++:
//  - W2/W3 stored f32 (EXACT: inputs are fp32; (double)w32 lossless; same
//    summation order -> bit-identical trajectory). Stream halves; dwordx16
//    carries 16 weights. Cost: 1 v_cvt_f64_f32 per MAC.
//  - Explicit 2-ahead prefetch: L2 ping-pong 8-f32 chunks; L3 3-buffer
//    rotation of 16-f32 chunks (static indices under full unroll).
//  - h2 tile of 8 (16 tiles) -> static code ~16 KB (I$-safe), V ~100.
// W1/b*/W4 stay f64 via SGPR (3 KB, K$-resident).

#define NDBL 771      // doubles region: W1T 320 | b1 64 | b2 128 | b3 64 | W4 192 | b4 3
#define dW1T 0
#define dB1  320
#define dB2  384
#define dB3  512
#define dW4  576
#define dB4  768
#define NFLT 16384    // floats region: W2 [64][128] | W3 [128][64]
#define fW2  0
#define fW3  8192
#define NTOT (NDBL + NFLT)

__device__ __forceinline__ void store_softmax(float* __restrict__ out, size_t base,
                                              float a, float b, float c) {
    float m  = fmaxf(a, fmaxf(b, c));
    float e0 = expf(a - m);
    float e1 = expf(b - m);
    float e2 = expf(c - m);
    float s  = e0 + e1 + e2;
    out[base + 0] = e0 / s;
    out[base + 1] = e1 / s;
    out[base + 2] = e2 / s;
}

__global__ __launch_bounds__(128, 2) void sir_rk4_kernel(
    const float* __restrict__ y0,   const float* __restrict__ tspan,
    const float* __restrict__ beta, const float* __restrict__ gamma,
    const double* __restrict__ PD,  const float* __restrict__ PF,
    float* __restrict__ out, int B, int T)
{
    // h1 (L2 phase) and h3 (L4 phase) share this buffer. [elem][thread]:
    // lane-consecutive (2-way alias = free), own column -> no barriers.
    __shared__ float hbuf[64][128];

    const int tid = threadIdx.x;
    const int b = blockIdx.x * 128 + tid;
    if (b >= B) return;

    const double* W1T = PD + dW1T;
    const double* B1v = PD + dB1;
    const double* B2v = PD + dB2;
    const double* B3v = PD + dB3;
    const double* W4v = PD + dW4;
    const double* B4v = PD + dB4;
    const float*  W2f = PF + fW2;
    const float*  W3f = PF + fW3;

    double ys = (double)y0[b * 3 + 0];
    double yi = (double)y0[b * 3 + 1];
    double yr = (double)y0[b * 3 + 2];
    const double be = (double)beta[b];
    const double ga = (double)gamma[b];

    store_softmax(out, (size_t)b * 3, (float)ys, (float)yi, (float)yr);

    #pragma unroll 1
    for (int t = 0; t < T - 1; ++t) {
        double dt = (double)tspan[t + 1] - (double)tspan[t];

        double ks0 = 0.0, ks1 = 0.0, ks2 = 0.0;
        double zs = ys, zi = yi, zr = yr;

        #pragma unroll 1
        for (int st = 0; st < 4; ++st) {
            // ---- L1: 5 -> 64 (f64 SGPR weights, K$-resident) ----
            #pragma unroll 2
            for (int j = 0; j < 64; ++j) {
                const double* w = W1T + j * 5;
                double ta = fma(w[0], zs, B1v[j]);
                double tb = w[2] * zr;
                ta = fma(w[1], zi, ta);
                tb = fma(w[3], be, tb);
                ta = fma(w[4], ga, ta);
                hbuf[j][tid] = tanhf((float)(ta + tb));
            }

            double acc3[64];
            #pragma unroll
            for (int j = 0; j < 64; ++j) acc3[j] = B3v[j];

            // ---- L2+L3: 64 -> 128 -> 64, 16 tiles of 8 ----
            #pragma unroll 1
            for (int c = 0; c < 16; ++c) {
                double h2[8];
                #pragma unroll
                for (int k = 0; k < 8; ++k) h2[k] = B2v[c * 8 + k];

                const float* wt = W2f + c * 8;   // row chunks, stride 128 floats

                // L2: 2-ahead ping-pong over i (4 x 8-f32 SGPR buffers)
                float wb0[8], wb1[8], wb2[8], wb3[8];
                #pragma unroll
                for (int q = 0; q < 8; ++q) wb0[q] = wt[0 * 128 + q];
                #pragma unroll
                for (int q = 0; q < 8; ++q) wb1[q] = wt[1 * 128 + q];

                #pragma unroll 1
                for (int i = 0; i < 64; i += 4) {
                    #pragma unroll
                    for (int q = 0; q < 8; ++q) wb2[q] = wt[(i + 2) * 128 + q];
                    {
                        double hv = (double)hbuf[i][tid];
                        #pragma unroll
                        for (int q = 0; q < 8; ++q) h2[q] = fma((double)wb0[q], hv, h2[q]);
                    }
                    #pragma unroll
                    for (int q = 0; q < 8; ++q) wb3[q] = wt[(i + 3) * 128 + q];
                    {
                        double hv = (double)hbuf[i + 1][tid];
                        #pragma unroll
                        for (int q = 0; q < 8; ++q) h2[q] = fma((double)wb1[q], hv, h2[q]);
                    }
                    // i=60 -> rows 64/65: lands in W3 region of PF, in-bounds, never consumed
                    #pragma unroll
                    for (int q = 0; q < 8; ++q) wb0[q] = wt[(i + 4) * 128 + q];
                    {
                        double hv = (double)hbuf[i + 2][tid];
                        #pragma unroll
                        for (int q = 0; q < 8; ++q) h2[q] = fma((double)wb2[q], hv, h2[q]);
                    }
                    #pragma unroll
                    for (int q = 0; q < 8; ++q) wb1[q] = wt[(i + 5) * 128 + q];
                    {
                        double hv = (double)hbuf[i + 3][tid];
                        #pragma unroll
                        for (int q = 0; q < 8; ++q) h2[q] = fma((double)wb3[q], hv, h2[q]);
                    }
                }

                // L3: 8 rows of 64, consumed as 32 chunks of 16 f32,
                // 3-buffer rotation loaded 2 chunks ahead (static under unroll).
                const float* w3t = W3f + c * 512;   // this tile's 8x64 block, contiguous
                float ub[3][16];
                #pragma unroll
                for (int q = 0; q < 16; ++q) ub[0][q] = w3t[q];
                #pragma unroll
                for (int q = 0; q < 16; ++q) ub[1][q] = w3t[16 + q];

                #pragma unroll
                for (int kk = 0; kk < 8; ++kk) {
                    double h = (double)tanhf((float)h2[kk]);
                    #pragma unroll
                    for (int q4 = 0; q4 < 4; ++q4) {
                        const int p = kk * 4 + q4;
                        if (p + 2 < 32) {
                            #pragma unroll
                            for (int q = 0; q < 16; ++q)
                                ub[(p + 2) % 3][q] = w3t[(p + 2) * 16 + q];
                        }
                        #pragma unroll
                        for (int j = 0; j < 16; ++j)
                            acc3[q4 * 16 + j] = fma((double)ub[p % 3][j], h, acc3[q4 * 16 + j]);
                    }
                }
            }

            // ---- L4: 64 -> 3 via LDS round-trip (acc3 is AGPR-resident) ----
            #pragma unroll
            for (int j = 0; j < 64; ++j) hbuf[j][tid] = (float)acc3[j];

            double e0 = B4v[0], e1 = B4v[1], e2 = B4v[2];
            #pragma unroll 2
            for (int j = 0; j < 64; ++j) {
                double h = (double)tanhf(hbuf[j][tid]);
                const double* w4 = W4v + j * 3;
                e0 = fma(w4[0], h, e0);
                e1 = fma(w4[1], h, e1);
                e2 = fma(w4[2], h, e2);
            }

            double w = (st == 1 || st == 2) ? 2.0 : 1.0;
            ks0 = fma(w, e0, ks0);
            ks1 = fma(w, e1, ks1);
            ks2 = fma(w, e2, ks2);
            double a = (st < 2) ? 0.5 * dt : dt;
            zs = fma(a, e0, ys);
            zi = fma(a, e1, yi);
            zr = fma(a, e2, yr);
        }

        double c6 = dt * (1.0 / 6.0);
        ys = fma(c6, ks0, ys);
        yi = fma(c6, ks1, yi);
        yr = fma(c6, ks2, yr);

        store_softmax(out, ((size_t)(t + 1) * B + b) * 3, (float)ys, (float)yi, (float)yr);
    }
}

// Stage: doubles region (W1 transposed [64][5], biases, W4) + floats region (W2, W3 as-is).
__global__ void stage_params_kernel(
    const float* __restrict__ W1, const float* __restrict__ b1,
    const float* __restrict__ W2, const float* __restrict__ b2,
    const float* __restrict__ W3, const float* __restrict__ b3,
    const float* __restrict__ W4, const float* __restrict__ b4,
    double* __restrict__ PD, float* __restrict__ PF)
{
    int idx = blockIdx.x * blockDim.x + threadIdx.x;
    if (idx >= NTOT) return;
    if (idx < NDBL) {
        float v;
        if (idx < dB1)      { int u = idx - dW1T; int j = u / 5; int q = u % 5; v = W1[q * 64 + j]; }
        else if (idx < dB2) v = b1[idx - dB1];
        else if (idx < dB3) v = b2[idx - dB2];
        else if (idx < dW4) v = b3[idx - dB3];
        else if (idx < dB4) v = W4[idx - dW4];
        else                v = b4[idx - dB4];
        PD[idx] = (double)v;
    } else {
        int f = idx - NDBL;
        PF[f] = (f < fW3) ? W2[f] : W3[f - fW3];
    }
}

extern "C" void kernel_launch(void* const* d_in, const int* in_sizes, int n_in,
                              void* d_out, int out_size, void* d_ws, size_t ws_size,
                              hipStream_t stream) {
    const float* y0    = (const float*)d_in[0];
    const float* tspan = (const float*)d_in[1];
    const float* beta  = (const float*)d_in[2];
    const float* gamma = (const float*)d_in[3];
    const float* W1    = (const float*)d_in[4];
    const float* b1    = (const float*)d_in[5];
    const float* W2    = (const float*)d_in[6];
    const float* b2    = (const float*)d_in[7];
    const float* W3    = (const float*)d_in[8];
    const float* b3    = (const float*)d_in[9];
    const float* W4    = (const float*)d_in[10];
    const float* b4    = (const float*)d_in[11];

    int B = in_sizes[0] / 3;
    int T = in_sizes[1];
    float* out = (float*)d_out;

    double* PD = (double*)d_ws;
    float*  PF = (float*)((char*)d_ws + (size_t)NDBL * sizeof(double));

    stage_params_kernel<<<(NTOT + 255) / 256, 256, 0, stream>>>(
        W1, b1, W2, b2, W3, b3, W4, b4, PD, PF);

    int blocks = (B + 127) / 128;
    sir_rk4_kernel<<<blocks, 128, 0, stream>>>(
        y0, tspan, beta, gamma, PD, PF, out, B, T);
}